// Round 2
// baseline (588.393 us; speedup 1.0000x reference)
//
#include <hip/hip_runtime.h>

#define N_MOSSY   4096
#define N_GRANULE 16384
#define K_TOP     491
#define M_SPLIT   16
#define M_PER     (N_MOSSY / M_SPLIT)   // 256 mossy fibers per block
#define G_BLOCKS  (N_GRANULE / 256)     // 64

// ---------------------------------------------------------------------------
// Kernel 1: partial g_exc sums.
// grid = (M_SPLIT, G_BLOCKS), block = 256.
// Block (mb, gb) handles m in [mb*256, mb*256+256), g in [gb*256, gb*256+256).
// Builds an ORDERED compacted active-m list (ballot-based), then thread-per-g
// accumulates W[g,m]*eff[m,g] over active m only.
//  - eff reads: lanes hit consecutive g -> perfectly coalesced (and we skip
//    80% of eff rows entirely).
//  - W reads: gather within each thread's own contiguous row; ascending list
//    gives each 64B line ~3.2x reuse through L1/L2.
// ---------------------------------------------------------------------------
__global__ __launch_bounds__(256) void gexc_partial(
    const float* __restrict__ spikes,
    const float* __restrict__ eff,
    const float* __restrict__ W,
    float* __restrict__ partial)
{
    __shared__ int s_act[M_PER];
    __shared__ int s_cnt[4];
    __shared__ int s_off[5];

    const int tid  = threadIdx.x;
    const int lane = tid & 63;
    const int wv   = tid >> 6;
    const int mb   = blockIdx.x;
    const int gb   = blockIdx.y;
    const int ms   = mb * M_PER;

    // ordered compaction of active m (4 waves x 64 lanes = 256 m)
    const int m    = ms + wv * 64 + lane;
    const bool p   = spikes[m] > 0.0f;
    const unsigned long long mk = __ballot(p);
    const int pre  = __popcll(mk & ((1ull << lane) - 1ull));
    if (lane == 0) s_cnt[wv] = __popcll(mk);
    __syncthreads();
    if (tid == 0) {
        int o = 0;
        for (int c = 0; c < 4; ++c) { s_off[c] = o; o += s_cnt[c]; }
        s_off[4] = o;
    }
    __syncthreads();
    if (p) s_act[s_off[wv] + pre] = m;
    __syncthreads();
    const int nact = s_off[4];

    const int g = gb * 256 + tid;
    const float* __restrict__ wrow = W + (size_t)g * N_MOSSY;

    float acc = 0.0f;
    int j = 0;
    for (; j + 4 <= nact; j += 4) {
        const int m0 = s_act[j + 0], m1 = s_act[j + 1];
        const int m2 = s_act[j + 2], m3 = s_act[j + 3];
        const float w0 = wrow[m0], w1 = wrow[m1], w2 = wrow[m2], w3 = wrow[m3];
        const float e0 = eff[(size_t)m0 * N_GRANULE + g];
        const float e1 = eff[(size_t)m1 * N_GRANULE + g];
        const float e2 = eff[(size_t)m2 * N_GRANULE + g];
        const float e3 = eff[(size_t)m3 * N_GRANULE + g];
        acc += w0 * e0; acc += w1 * e1; acc += w2 * e2; acc += w3 * e3;
    }
    for (; j < nact; ++j) {
        const int m0 = s_act[j];
        acc += wrow[m0] * eff[(size_t)m0 * N_GRANULE + g];
    }
    partial[(size_t)mb * N_GRANULE + g] = acc;
}

// ---------------------------------------------------------------------------
// Kernel 2: reduce partials -> g_exc, LIF threshold, exact top-K WTA.
// Single block of 1024 threads; each thread owns 16 g (coalesced i*1024+t).
// Exact top-K reproducing jax.lax.top_k tie-breaking:
//   g_exc >= 0 always (all inputs nonneg) -> float bits are order-preserving.
//   2048-bin histogram of bits>>17 (clamped), suffix scan to find cutoff bin,
//   exact (bits desc, idx asc) ranking within the cutoff bin.
// Output is the reference's bool -> int32 buffer: write 0/1 ints.
// ---------------------------------------------------------------------------
#define NB   2048
#define BIN0 7680   // (bits>>17) of 2^-7; bins cover [2^-7, 2^25)
#define CAP  2048

__global__ __launch_bounds__(1024) void reduce_select(
    const float* __restrict__ partial,
    int* __restrict__ out)
{
    __shared__ int s_hist[NB];
    __shared__ int s_scan[1024];
    __shared__ unsigned int s_cbits[CAP];
    __shared__ int s_cidx[CAP];
    __shared__ int s_ccnt;
    __shared__ int s_nspk;
    __shared__ int s_B;
    __shared__ int s_need;

    const int t = threadIdx.x;

    // reduce 16 partials per g (deterministic order)
    float gx[16];
    #pragma unroll
    for (int i = 0; i < 16; ++i) {
        const int g = i * 1024 + t;
        float a = 0.0f;
        #pragma unroll
        for (int s = 0; s < M_SPLIT; ++s)
            a += partial[(size_t)s * N_GRANULE + g];
        gx[i] = a;
    }

    // conductance-LIF step: v = -65 + 0.2*(0 + g*65); spike iff v >= -50
    unsigned int ubits[16];
    int spkmask = 0;
    int myspk = 0;
    #pragma unroll
    for (int i = 0; i < 16; ++i) {
        const float dv = 0.2f * (0.0f + gx[i] * 65.0f);
        const float v  = -65.0f + dv;
        const bool s   = (v >= -50.0f);
        if (s) { spkmask |= (1 << i); ++myspk; }
        ubits[i] = __float_as_uint(gx[i]);
    }

    if (t == 0) { s_ccnt = 0; s_nspk = 0; s_B = -1; s_need = 0; }
    for (int b = t; b < NB; b += 1024) s_hist[b] = 0;
    __syncthreads();

    atomicAdd(&s_nspk, myspk);
    #pragma unroll
    for (int i = 0; i < 16; ++i) {
        if ((spkmask >> i) & 1) {
            int b = (int)(ubits[i] >> 17) - BIN0;
            b = b < 0 ? 0 : (b >= NB ? NB - 1 : b);
            atomicAdd(&s_hist[b], 1);
        }
    }
    __syncthreads();

    const int nspk = s_nspk;

    if (nspk > K_TOP) {
        // inclusive suffix sum over 2048 bins (2 bins/thread + Hillis-Steele)
        s_scan[t] = s_hist[2 * t] + s_hist[2 * t + 1];
        __syncthreads();
        for (int off = 1; off < 1024; off <<= 1) {
            const int v = (t + off < 1024) ? s_scan[t + off] : 0;
            __syncthreads();
            s_scan[t] += v;
            __syncthreads();
        }
        // s_scan[t] = sum of bins >= 2t
        const int suf0 = s_scan[t];                     // incl. suffix at bin 2t
        const int suf1 = s_scan[t] - s_hist[2 * t];     // incl. suffix at bin 2t+1
        if (suf0 >= K_TOP) atomicMax(&s_B, 2 * t);
        if (suf1 >= K_TOP) atomicMax(&s_B, 2 * t + 1);
        __syncthreads();
        const int B = s_B;
        if (t == 0) {
            const int sufB = s_scan[B >> 1] - ((B & 1) ? s_hist[B & ~1] : 0);
            s_need = K_TOP - (sufB - s_hist[B]);        // how many from bin B
        }
        __syncthreads();
        const int need = s_need;

        // collect cutoff-bin candidates
        #pragma unroll
        for (int i = 0; i < 16; ++i) {
            if ((spkmask >> i) & 1) {
                int b = (int)(ubits[i] >> 17) - BIN0;
                b = b < 0 ? 0 : (b >= NB ? NB - 1 : b);
                if (b == B) {
                    const int pos = atomicAdd(&s_ccnt, 1);
                    if (pos < CAP) {
                        s_cbits[pos] = ubits[i];
                        s_cidx[pos]  = i * 1024 + t;
                    }
                }
            }
        }
        __syncthreads();
        int C = s_ccnt; if (C > CAP) C = CAP;

        #pragma unroll
        for (int i = 0; i < 16; ++i) {
            const int g = i * 1024 + t;
            bool sel = false;
            if ((spkmask >> i) & 1) {
                int b = (int)(ubits[i] >> 17) - BIN0;
                b = b < 0 ? 0 : (b >= NB ? NB - 1 : b);
                if (b > B) {
                    sel = true;
                } else if (b == B) {
                    // rank among candidates: (bits desc, idx asc) like top_k
                    int rank = 0;
                    for (int j = 0; j < C; ++j) {
                        const unsigned int cb = s_cbits[j];
                        const int ci = s_cidx[j];
                        if (cb > ubits[i] || (cb == ubits[i] && ci < g)) ++rank;
                    }
                    sel = (rank < need);
                }
            }
            out[g] = sel ? 1 : 0;
        }
    } else {
        #pragma unroll
        for (int i = 0; i < 16; ++i) {
            const int g = i * 1024 + t;
            out[g] = ((spkmask >> i) & 1) ? 1 : 0;
        }
    }
}

extern "C" void kernel_launch(void* const* d_in, const int* in_sizes, int n_in,
                              void* d_out, int out_size, void* d_ws, size_t ws_size,
                              hipStream_t stream) {
    const float* spikes = (const float*)d_in[0];  // [4096]
    const float* eff    = (const float*)d_in[1];  // [4096, 16384]
    const float* W      = (const float*)d_in[2];  // [16384, 4096]
    int* out       = (int*)d_out;                 // [16384] bool -> int32 0/1
    float* partial = (float*)d_ws;                // [M_SPLIT, 16384] floats

    gexc_partial<<<dim3(M_SPLIT, G_BLOCKS), 256, 0, stream>>>(spikes, eff, W, partial);
    reduce_select<<<1, 1024, 0, stream>>>(partial, out);
}

// Round 3
// 524.368 us; speedup vs baseline: 1.1221x; 1.1221x over previous
//
#include <hip/hip_runtime.h>

#define N_MOSSY   4096
#define N_GRANULE 16384
#define K_TOP     491
#define M_SPLIT   16
#define M_PER     256           // mossy fibers per block (N_MOSSY / M_SPLIT)
#define G_BLOCKS  64            // N_GRANULE / 256
#define CH        32            // m-chunk staged in LDS
#define NCH       (M_PER / CH)  // 8
#define LDS_PAD   257           // stride 257: bank = (m + g) % 32 -> read conflict-free

#define NB   2048
#define BIN0 7680               // (bits>>17) of 2^-7
#define CAP  2048

// ws layout (4-byte units)
#define WS_PARTIAL 0
#define WS_UBITS   (M_SPLIT * N_GRANULE)
#define WS_HIST    (WS_UBITS + N_GRANULE)
#define WS_NSPK    (WS_HIST + NB)

// ---------------------------------------------------------------------------
// Kernel 1: partial g_exc sums, LDS-staged W.
// grid = (M_SPLIT, G_BLOCKS), block = 256.
// Per m-chunk of 32: stage W[256 g][32 m] into LDS transposed (coalesced
// float4 global loads; padded stride-257 LDS so compute reads are
// conflict-free), then accumulate over the ORDERED active-m list:
//   acc += wl[m_local][g_local] * eff[m][g]   (eff coalesced across lanes)
// This removes the 64-lines-per-instruction W gather that was L1-bound.
// Also zeroes the global histogram/nspk (mb==0 blocks) for kernel 2a.
// ---------------------------------------------------------------------------
__global__ __launch_bounds__(256) void gexc_partial(
    const float* __restrict__ spikes,
    const float* __restrict__ eff,
    const float* __restrict__ W,
    float* __restrict__ partial,
    int* __restrict__ hist,
    int* __restrict__ nspk)
{
    __shared__ float wl[CH][LDS_PAD];
    __shared__ int s_act[M_PER];
    __shared__ int s_cnt[4];
    __shared__ int s_off[5];

    const int tid  = threadIdx.x;
    const int lane = tid & 63;
    const int wv   = tid >> 6;
    const int mb   = blockIdx.x;
    const int gb   = blockIdx.y;
    const int ms   = mb * M_PER;

    // zero global scratch for kernel 2a (in-stream kernel order makes this safe)
    if (mb == 0) {
        if (gb < 8) hist[gb * 256 + tid] = 0;
        else if (gb == 8 && tid == 0) *nspk = 0;
    }

    // ordered compaction of active m (4 waves x 64 lanes = 256 m)
    const int m0   = ms + wv * 64 + lane;
    const bool p   = spikes[m0] > 0.0f;
    const unsigned long long mk = __ballot(p);
    const int pre  = __popcll(mk & ((1ull << lane) - 1ull));
    if (lane == 0) s_cnt[wv] = __popcll(mk);
    __syncthreads();
    if (tid == 0) {
        int o = 0;
        for (int c = 0; c < 4; ++c) { s_off[c] = o; o += s_cnt[c]; }
        s_off[4] = o;
    }
    __syncthreads();
    if (p) s_act[s_off[wv] + pre] = m0;
    __syncthreads();
    const int nact = s_off[4];

    const int g = gb * 256 + tid;

    float acc = 0.0f;
    int j = 0;
    for (int c = 0; c < NCH; ++c) {
        // stage chunk: 256 g x 32 m = 2048 float4, 8 per thread, coalesced
        #pragma unroll
        for (int i = 0; i < 8; ++i) {
            const int f  = i * 256 + tid;
            const int gl = f >> 3;          // 0..255
            const int m4 = f & 7;           // 0..7 (float4 index within chunk)
            const float4 v = *reinterpret_cast<const float4*>(
                &W[(size_t)(gb * 256 + gl) * N_MOSSY + ms + c * CH + m4 * 4]);
            wl[m4 * 4 + 0][gl] = v.x;
            wl[m4 * 4 + 1][gl] = v.y;
            wl[m4 * 4 + 2][gl] = v.z;
            wl[m4 * 4 + 3][gl] = v.w;
        }
        __syncthreads();
        const int cend = ms + (c + 1) * CH;
        const int cbase = ms + c * CH;
        while (j < nact && s_act[j] < cend) {
            const int m = s_act[j];
            acc += wl[m - cbase][tid] * eff[(size_t)m * N_GRANULE + g];
            ++j;
        }
        __syncthreads();
    }
    partial[(size_t)mb * N_GRANULE + g] = acc;
}

// ---------------------------------------------------------------------------
// Kernel 2a: parallel reduction of the 16 partials + LIF + global histogram.
// grid = 16 blocks x 1024 threads (one thread per granule cell).
// ---------------------------------------------------------------------------
__global__ __launch_bounds__(1024) void reduce_lif(
    const float* __restrict__ partial,
    unsigned int* __restrict__ ubits,
    int* __restrict__ hist,
    int* __restrict__ nspk)
{
    const int g = blockIdx.x * 1024 + threadIdx.x;
    float a = 0.0f;
    #pragma unroll
    for (int s = 0; s < M_SPLIT; ++s)
        a += partial[(size_t)s * N_GRANULE + g];
    const unsigned int ub = __float_as_uint(a);
    ubits[g] = ub;
    const float v = -65.0f + 0.2f * (0.0f + a * 65.0f);
    const bool sp = (v >= -50.0f);
    const unsigned long long mk = __ballot(sp);
    if ((threadIdx.x & 63) == 0) atomicAdd(nspk, __popcll(mk));
    if (sp) {
        int b = (int)(ub >> 17) - BIN0;
        b = b < 0 ? 0 : (b >= NB ? NB - 1 : b);
        atomicAdd(&hist[b], 1);
    }
}

// ---------------------------------------------------------------------------
// Kernel 2b: exact top-K selection (single block, 1024 threads, reads 72 KB).
// Suffix-scan the 2048-bin histogram to find the cutoff bin B and `need`,
// then exact (bits desc, idx asc) ranking within bin B — reproduces
// jax.lax.top_k tie-breaking. Output: int32 0/1.
// ---------------------------------------------------------------------------
__global__ __launch_bounds__(1024) void select_topk(
    const unsigned int* __restrict__ ubits,
    const int* __restrict__ hist,
    const int* __restrict__ nspk,
    int* __restrict__ out)
{
    __shared__ int s_hist[NB];
    __shared__ int s_scan[1024];
    __shared__ unsigned int s_cbits[CAP];
    __shared__ int s_cidx[CAP];
    __shared__ int s_ccnt;
    __shared__ int s_B;
    __shared__ int s_need;

    const int t = threadIdx.x;

    unsigned int u[16];
    int spkmask = 0;
    #pragma unroll
    for (int i = 0; i < 16; ++i) {
        u[i] = ubits[i * 1024 + t];
        const float a = __uint_as_float(u[i]);
        const float v = -65.0f + 0.2f * (0.0f + a * 65.0f);
        if (v >= -50.0f) spkmask |= (1 << i);
    }
    s_hist[t] = hist[t];
    s_hist[t + 1024] = hist[t + 1024];
    if (t == 0) { s_ccnt = 0; s_B = -1; s_need = 0; }
    __syncthreads();

    const int ns = *nspk;

    if (ns > K_TOP) {
        // inclusive suffix sum over 2048 bins (2 bins/thread + Hillis-Steele)
        s_scan[t] = s_hist[2 * t] + s_hist[2 * t + 1];
        __syncthreads();
        for (int off = 1; off < 1024; off <<= 1) {
            const int v = (t + off < 1024) ? s_scan[t + off] : 0;
            __syncthreads();
            s_scan[t] += v;
            __syncthreads();
        }
        const int suf0 = s_scan[t];                  // suffix at bin 2t
        const int suf1 = s_scan[t] - s_hist[2 * t];  // suffix at bin 2t+1
        if (suf0 >= K_TOP) atomicMax(&s_B, 2 * t);
        if (suf1 >= K_TOP) atomicMax(&s_B, 2 * t + 1);
        __syncthreads();
        const int B = s_B;
        if (t == 0) {
            const int sufB = s_scan[B >> 1] - ((B & 1) ? s_hist[B & ~1] : 0);
            s_need = K_TOP - (sufB - s_hist[B]);     // how many from bin B
        }
        __syncthreads();
        const int need = s_need;

        // collect cutoff-bin candidates
        #pragma unroll
        for (int i = 0; i < 16; ++i) {
            if ((spkmask >> i) & 1) {
                int b = (int)(u[i] >> 17) - BIN0;
                b = b < 0 ? 0 : (b >= NB ? NB - 1 : b);
                if (b == B) {
                    const int pos = atomicAdd(&s_ccnt, 1);
                    if (pos < CAP) {
                        s_cbits[pos] = u[i];
                        s_cidx[pos]  = i * 1024 + t;
                    }
                }
            }
        }
        __syncthreads();
        int C = s_ccnt; if (C > CAP) C = CAP;

        #pragma unroll
        for (int i = 0; i < 16; ++i) {
            const int g = i * 1024 + t;
            bool sel = false;
            if ((spkmask >> i) & 1) {
                int b = (int)(u[i] >> 17) - BIN0;
                b = b < 0 ? 0 : (b >= NB ? NB - 1 : b);
                if (b > B) {
                    sel = true;
                } else if (b == B) {
                    int rank = 0;
                    for (int jj = 0; jj < C; ++jj) {
                        const unsigned int cb = s_cbits[jj];
                        const int ci = s_cidx[jj];
                        if (cb > u[i] || (cb == u[i] && ci < g)) ++rank;
                    }
                    sel = (rank < need);
                }
            }
            out[g] = sel ? 1 : 0;
        }
    } else {
        #pragma unroll
        for (int i = 0; i < 16; ++i) {
            const int g = i * 1024 + t;
            out[g] = ((spkmask >> i) & 1) ? 1 : 0;
        }
    }
}

extern "C" void kernel_launch(void* const* d_in, const int* in_sizes, int n_in,
                              void* d_out, int out_size, void* d_ws, size_t ws_size,
                              hipStream_t stream) {
    const float* spikes = (const float*)d_in[0];  // [4096]
    const float* eff    = (const float*)d_in[1];  // [4096, 16384]
    const float* W      = (const float*)d_in[2];  // [16384, 4096]
    int* out = (int*)d_out;                       // [16384] bool -> int32 0/1

    float*        partial = (float*)d_ws + WS_PARTIAL;
    unsigned int* ubits   = (unsigned int*)d_ws + WS_UBITS;
    int*          hist    = (int*)d_ws + WS_HIST;
    int*          nspk    = (int*)d_ws + WS_NSPK;

    gexc_partial<<<dim3(M_SPLIT, G_BLOCKS), 256, 0, stream>>>(spikes, eff, W,
                                                              partial, hist, nspk);
    reduce_lif<<<M_SPLIT, 1024, 0, stream>>>(partial, ubits, hist, nspk);
    select_topk<<<1, 1024, 0, stream>>>(ubits, hist, nspk, out);
}